// Round 1
// baseline (955.505 us; speedup 1.0000x reference)
//
#include <hip/hip_runtime.h>
#include <cstdint>
#include <cstddef>

constexpr int kBS = 8;
constexpr int kNC = 64;
constexpr int kC = 256;
constexpr int kD = 32;
constexpr int kK = 16;
constexpr int kKB = 8;
constexpr int kALPHA = 4;
constexpr int kB = 16;
constexpr int kHS = 64;
constexpr int kHM = 64;
constexpr int kHMOD = 32;
constexpr int kN = kNC * kC;               // 16384
constexpr int kMODIN = kK + 3 * kD + 1;    // 113
constexpr int kMODOUT = kK + kKB + 1 + kD; // 57
constexpr int kW1Stride = 120;             // padded, 16B aligned rows
constexpr int kW2Stride = 60;              // padded, 16B aligned rows

constexpr size_t kO1 = (size_t)kBS * kNC * kD;        // readout size = 16384
constexpr size_t kO2 = kO1 + (size_t)kBS * kN * kD;   // + h_new
constexpr size_t kO3 = kO2 + (size_t)kBS * kN * kD;   // + msg

__device__ __forceinline__ float sigmoidf_(float x) {
    return 1.0f / (1.0f + __expf(-x));
}

// ---------------- Kernel A: per-neuron modulation MLP --------------------
// One wave (64 threads) per neuron n; computes out[b][57] for all 8 batches.
__global__ __launch_bounds__(64) void mod_mlp_kernel(
    const float* __restrict__ heb, const float* __restrict__ h,
    const float* __restrict__ dlog, const float* __restrict__ prim,
    const float* __restrict__ nid,
    const float* __restrict__ mw1, const float* __restrict__ mb1,
    const float* __restrict__ mw2, const float* __restrict__ mb2,
    float* __restrict__ modout)
{
    const int n = blockIdx.x;
    const int lane = threadIdx.x;

    __shared__ __align__(16) float w1s[kHMOD * kW1Stride]; // 3840 f; reused for W2
    __shared__ __align__(16) float flats[kBS * kW1Stride]; // 960 f
    __shared__ float hids[kBS * kHMOD];                    // 256 f
    __shared__ float b1s[kHMOD];
    __shared__ float b2s[kMODOUT];

    // stage W1 (coalesced global reads, padded LDS rows)
    const float* w1g = mw1 + (size_t)n * (kHMOD * kMODIN);
    for (int idx = lane; idx < kHMOD * kMODIN; idx += 64) {
        int r = idx / kMODIN;
        int ci = idx - r * kMODIN;
        w1s[r * kW1Stride + ci] = w1g[idx];
    }
    if (lane < kHMOD) b1s[lane] = mb1[(size_t)n * kHMOD + lane];

    // stage mod input vectors for all 8 batches
    for (int t = lane; t < kBS * kMODIN; t += 64) {
        int b = t / kMODIN;
        int i = t - b * kMODIN;
        size_t nb = (size_t)b * kN + n;
        float v;
        if (i < kK)                 v = heb[nb * kK + i];
        else if (i < kK + kD)       v = h[nb * kD + (i - kK)];
        else if (i == kK + kD)      v = dlog[nb];
        else if (i < kK + 2*kD + 1) v = prim[nb * kD + (i - (kK + kD + 1))];
        else                        v = nid[(size_t)n * kD + (i - (kK + 2*kD + 1))];
        flats[b * kW1Stride + i] = v;
    }
    __syncthreads();

    // layer 1: 256 (b,hh) dot products of length 113, 4 per lane
    #pragma unroll
    for (int j = 0; j < 4; ++j) {
        int t = lane + 64 * j;
        int b = t >> 5;
        int hh = t & 31;
        const float4* wr = (const float4*)(w1s + hh * kW1Stride);
        const float4* xr = (const float4*)(flats + b * kW1Stride);
        float acc = b1s[hh];
        #pragma unroll
        for (int q = 0; q < 28; ++q) {
            float4 wv = wr[q], xv = xr[q];
            acc += xv.x * wv.x; acc += xv.y * wv.y;
            acc += xv.z * wv.z; acc += xv.w * wv.w;
        }
        acc += w1s[hh * kW1Stride + 112] * flats[b * kW1Stride + 112];
        hids[b * kHMOD + hh] = tanhf(acc);
    }
    __syncthreads();

    // stage W2 into the (now free) W1 buffer
    const float* w2g = mw2 + (size_t)n * (kHMOD * kMODOUT);
    for (int idx = lane; idx < kHMOD * kMODOUT; idx += 64) {
        int r = idx / kMODOUT;
        int ci = idx - r * kMODOUT;
        w1s[r * kW2Stride + ci] = w2g[idx];
    }
    if (lane < kMODOUT) b2s[lane] = mb2[(size_t)n * kMODOUT + lane];
    __syncthreads();

    // layer 2: 456 (b,o) dots of length 32; coalesced write to workspace
    for (int t = lane; t < kBS * kMODOUT; t += 64) {
        int b = t / kMODOUT;
        int o = t - b * kMODOUT;
        const float* hrow = hids + b * kHMOD;
        float acc = b2s[o];
        #pragma unroll
        for (int hh = 0; hh < kHMOD; ++hh) acc += hrow[hh] * w1s[hh * kW2Stride + o];
        modout[((size_t)b * kN + n) * kMODOUT + o] = acc;
    }
}

// ---------------- Kernel B: per-cell message passing + state/msg MLPs -----
// One block per (b,nc); one thread per neuron c.
__global__ __launch_bounds__(256) void cell_kernel(
    const float* __restrict__ cc, const float* __restrict__ hin,
    const float* __restrict__ pmsg, const float* __restrict__ prim,
    const float* __restrict__ hebin, const float* __restrict__ nid,
    const float* __restrict__ sw1, const float* __restrict__ sb1,
    const float* __restrict__ sw2, const float* __restrict__ sb2,
    const float* __restrict__ mw1g, const float* __restrict__ mb1g,
    const float* __restrict__ mw2g, const float* __restrict__ mb2g,
    const int* __restrict__ conn, const int* __restrict__ bconn,
    const float* __restrict__ modout, float* __restrict__ out)
{
    const int nc = blockIdx.x;
    const int b  = blockIdx.y;
    const int c  = threadIdx.x;

    __shared__ float slab[kC * 33]; // stride-33 pad: gather banks = (j+d)%32

    const size_t cellrow = ((size_t)b * kNC + nc) * kC; // (b,nc,0) flat neuron idx
    const size_t nbase   = cellrow + c;

    // stage this cell's prev_messages (coalesced)
    {
        const float* src = pmsg + cellrow * kD;
        for (int i = c; i < kC * kD; i += kC) {
            int r = i >> 5, d = i & 31;
            slab[r * 33 + d] = src[i];
        }
    }

    // per-thread loads (overlap with staging)
    float hreg[32];
    {
        const float4* src = (const float4*)(hin + nbase * kD);
        #pragma unroll
        for (int q = 0; q < 8; ++q) {
            float4 v = src[q];
            hreg[4*q] = v.x; hreg[4*q+1] = v.y; hreg[4*q+2] = v.z; hreg[4*q+3] = v.w;
        }
    }
    const float* mo = modout + nbase * kMODOUT;
    float wcon[16];
    #pragma unroll
    for (int k = 0; k < 16; ++k) wcon[k] = sigmoidf_(mo[k]);
    int jreg[16];
    {
        const int4* cr = (const int4*)(conn + ((size_t)nc * kC + c) * kK);
        #pragma unroll
        for (int q = 0; q < 4; ++q) {
            int4 v = cr[q];
            jreg[4*q] = v.x; jreg[4*q+1] = v.y; jreg[4*q+2] = v.z; jreg[4*q+3] = v.w;
        }
    }
    const float decay = sigmoidf_(mo[kK + kKB]);
    float pnew[32];
    {
        const float4* src = (const float4*)(prim + nbase * kD);
        #pragma unroll
        for (int q = 0; q < 8; ++q) {
            float4 v = src[q];
            pnew[4*q]   = v.x + mo[kK + kKB + 1 + 4*q];
            pnew[4*q+1] = v.y + mo[kK + kKB + 1 + 4*q + 1];
            pnew[4*q+2] = v.z + mo[kK + kKB + 1 + 4*q + 2];
            pnew[4*q+3] = v.w + mo[kK + kKB + 1 + 4*q + 3];
        }
    }
    __syncthreads();

    // received = sum_k sigmoid(w_conn[k]) * prev_msg[conn[k]]
    float recv[32];
    #pragma unroll
    for (int d = 0; d < 32; ++d) recv[d] = 0.f;
    #pragma unroll 1
    for (int k = 0; k < 16; ++k) {
        const float* row = slab + jreg[k] * 33;
        const float w = wcon[k];
        #pragma unroll
        for (int d = 0; d < 32; ++d) recv[d] += row[d] * w;
    }
    // border contributions (neurons 4..19)
    if (c >= kALPHA && c < kALPHA + kB) {
        const int j = c - kALPHA;
        const int* br = bconn + ((size_t)nc * kB + j) * kKB;
        #pragma unroll 1
        for (int kb = 0; kb < kKB; ++kb) {
            int g = br[kb];                // in [0, NC*B)
            int nc2 = g >> 4;
            int c2 = kALPHA + (g & 15);
            const float* src = pmsg + (((size_t)b * kNC + nc2) * kC + c2) * kD;
            float w = sigmoidf_(mo[kK + kb]);
            #pragma unroll
            for (int d = 0; d < 32; ++d) recv[d] += src[d] * w;
        }
    }
    // cc injection (neurons 0..3)
    if (c < kALPHA) {
        const float* src = cc + (size_t)b * (kNC * kD) + nc * kD;
        #pragma unroll
        for (int d = 0; d < 32; ++d) recv[d] += src[d];
    }

    // state MLP: s_in = [h(32), recv(32), pnew(32), decay]
    float dh[32];
    #pragma unroll
    for (int o = 0; o < 32; ++o) dh[o] = sb2[o];
    #pragma unroll 4
    for (int hh = 0; hh < kHS; ++hh) {
        const float* w = sw1 + hh * (3 * kD + 1);   // uniform -> s_load
        float acc = sb1[hh];
        #pragma unroll
        for (int i = 0; i < 32; ++i) acc += hreg[i] * w[i];
        #pragma unroll
        for (int i = 0; i < 32; ++i) acc += recv[i] * w[32 + i];
        #pragma unroll
        for (int i = 0; i < 32; ++i) acc += pnew[i] * w[64 + i];
        acc += decay * w[96];
        const float s = tanhf(acc);
        #pragma unroll
        for (int o = 0; o < 32; ++o) dh[o] += s * sw2[o * kHS + hh];
    }
    float hnew[32];
    #pragma unroll
    for (int d = 0; d < 32; ++d) hnew[d] = decay * hreg[d] + (1.f - decay) * tanhf(dh[d]);

    // write h_new
    {
        float4* dst = (float4*)(out + kO1 + nbase * kD);
        #pragma unroll
        for (int q = 0; q < 8; ++q)
            dst[q] = make_float4(hnew[4*q], hnew[4*q+1], hnew[4*q+2], hnew[4*q+3]);
    }

    // msg MLP: m_in = [h_new(32), recv(32), nid(32)]
    float nidr[32];
    {
        const float4* src = (const float4*)(nid + ((size_t)nc * kC + c) * kD);
        #pragma unroll
        for (int q = 0; q < 8; ++q) {
            float4 v = src[q];
            nidr[4*q] = v.x; nidr[4*q+1] = v.y; nidr[4*q+2] = v.z; nidr[4*q+3] = v.w;
        }
    }
    float mm[32];
    #pragma unroll
    for (int o = 0; o < 32; ++o) mm[o] = mb2g[o];
    #pragma unroll 4
    for (int hh = 0; hh < kHM; ++hh) {
        const float* w = mw1g + hh * (3 * kD);      // uniform -> s_load
        float acc = mb1g[hh];
        #pragma unroll
        for (int i = 0; i < 32; ++i) acc += hnew[i] * w[i];
        #pragma unroll
        for (int i = 0; i < 32; ++i) acc += recv[i] * w[32 + i];
        #pragma unroll
        for (int i = 0; i < 32; ++i) acc += nidr[i] * w[64 + i];
        const float s = tanhf(acc);
        #pragma unroll
        for (int o = 0; o < 32; ++o) mm[o] += s * mw2g[o * kHM + hh];
    }
    float msgr[32];
    #pragma unroll
    for (int d = 0; d < 32; ++d) msgr[d] = tanhf(mm[d]);

    __syncthreads();   // everyone done reading prev_messages from slab
    #pragma unroll
    for (int d = 0; d < 32; ++d) slab[c * 33 + d] = msgr[d];
    __syncthreads();

    // hebbian update: corr[k] = (msg . msg[conn[k]]) / D
    {
        const float* hb = hebin + nbase * kK;
        float* dst = out + kO3 + nbase * kK;
        #pragma unroll 1
        for (int k = 0; k < 16; ++k) {
            const float* row = slab + jreg[k] * 33;
            float dot = 0.f;
            #pragma unroll
            for (int d = 0; d < 32; ++d) dot += msgr[d] * row[d];
            dst[k] = 0.9f * hb[k] + 0.1f * (dot * (1.0f / 32.0f));
        }
    }
    // msg output, coalesced via LDS
    {
        float* dst = out + kO2 + cellrow * kD;
        for (int i = c; i < kC * kD; i += kC) {
            int r = i >> 5, d = i & 31;
            dst[i] = slab[r * 33 + d];
        }
    }
    // readout: mean of last ALPHA=4 neurons' msg
    if (c < kD) {
        float s = 0.25f * (slab[(kC-4)*33 + c] + slab[(kC-3)*33 + c] +
                           slab[(kC-2)*33 + c] + slab[(kC-1)*33 + c]);
        out[(size_t)b * (kNC * kD) + nc * kD + c] = s;
    }
}

extern "C" void kernel_launch(void* const* d_in, const int* in_sizes, int n_in,
                              void* d_out, int out_size, void* d_ws, size_t ws_size,
                              hipStream_t stream)
{
    const float* cc    = (const float*)d_in[0];
    const float* h     = (const float*)d_in[1];
    const float* pmsg  = (const float*)d_in[2];
    const float* dlog  = (const float*)d_in[3];
    const float* prim  = (const float*)d_in[4];
    const float* heb   = (const float*)d_in[5];
    const float* sw1   = (const float*)d_in[6];
    const float* sb1   = (const float*)d_in[7];
    const float* sw2   = (const float*)d_in[8];
    const float* sb2   = (const float*)d_in[9];
    const float* mw1   = (const float*)d_in[10];
    const float* mb1   = (const float*)d_in[11];
    const float* mw2   = (const float*)d_in[12];
    const float* mb2   = (const float*)d_in[13];
    const float* modw1 = (const float*)d_in[14];
    const float* modb1 = (const float*)d_in[15];
    const float* modw2 = (const float*)d_in[16];
    const float* modb2 = (const float*)d_in[17];
    const float* nid   = (const float*)d_in[18];
    const int*   conn  = (const int*)d_in[19];
    const int*   bconn = (const int*)d_in[20];
    float* out = (float*)d_out;
    float* modout = (float*)d_ws;   // (BS, N, 57) = 29.9 MB scratch

    mod_mlp_kernel<<<kN, 64, 0, stream>>>(heb, h, dlog, prim, nid,
                                          modw1, modb1, modw2, modb2, modout);
    cell_kernel<<<dim3(kNC, kBS), kC, 0, stream>>>(cc, h, pmsg, prim, heb, nid,
                                                   sw1, sb1, sw2, sb2,
                                                   mw1, mb1, mw2, mb2,
                                                   conn, bconn, modout, out);
}